// Round 4
// baseline (513.227 us; speedup 1.0000x reference)
//
#include <hip/hip_runtime.h>
#include <stdint.h>

// Problem constants (from reference setup_inputs)
#define B_DIM   16384
#define IN_DIM  2048
#define OUT_DIM 2048
#define BN_EPS  1e-5f

typedef int    i32x4 __attribute__((ext_vector_type(4)));
typedef unsigned short u16x4 __attribute__((ext_vector_type(4)));

// ---------- helpers ----------

__device__ __forceinline__ unsigned short f2bf_rne(float f) {
    unsigned u = __builtin_bit_cast(unsigned, f);
    return (unsigned short)((u + 0x7fffu + ((u >> 16) & 1u)) >> 16);
}
__device__ __forceinline__ float bf2f(unsigned short h) {
    unsigned u = ((unsigned)h) << 16;
    return __builtin_bit_cast(float, u);
}

// async global->LDS, 16B per lane. LDS dst = wave-uniform base + lane*16.
__device__ __forceinline__ void gl_lds16(const void* g, void* l) {
    __builtin_amdgcn_global_load_lds(
        (const __attribute__((address_space(1))) unsigned int*)g,
        (__attribute__((address_space(3))) unsigned int*)l,
        16, 0, 0);
}

__device__ __forceinline__ int pack4(float a, float b, float c, float d, float inv) {
    int q0 = (int)rintf(a * inv) & 255;
    int q1 = (int)rintf(b * inv) & 255;
    int q2 = (int)rintf(c * inv) & 255;
    int q3 = (int)rintf(d * inv) & 255;
    return q0 | (q1 << 8) | (q2 << 16) | (q3 << 24);
}

// ---------- kernel 1: x fp32 -> i8 with per-row scale ----------
__global__ __launch_bounds__(256) void quantize_x_kernel(
        const float4* __restrict__ x4, int* __restrict__ xq,
        float* __restrict__ scales) {
    __shared__ float wmax[4];
    const int row = blockIdx.x;
    const int t = threadIdx.x;
    const float4* xr = x4 + (size_t)row * 512;
    float4 a = xr[t];          // 16B coalesced
    float4 b = xr[t + 256];
    float m = fmaxf(fmaxf(fabsf(a.x), fabsf(a.y)), fmaxf(fabsf(a.z), fabsf(a.w)));
    m = fmaxf(m, fmaxf(fmaxf(fabsf(b.x), fabsf(b.y)), fmaxf(fabsf(b.z), fabsf(b.w))));
#pragma unroll
    for (int off = 32; off >= 1; off >>= 1) m = fmaxf(m, __shfl_xor(m, off));
    if ((t & 63) == 0) wmax[t >> 6] = m;
    __syncthreads();
    m = fmaxf(fmaxf(wmax[0], wmax[1]), fmaxf(wmax[2], wmax[3]));
    m = fmaxf(m, 1e-20f);                 // guard all-zero row
    const float inv = 127.0f / m;
    if (t == 0) scales[row] = m * (1.0f / 127.0f);
    int* xo = xq + (size_t)row * 512;
    xo[t]       = pack4(a.x, a.y, a.z, a.w, inv);   // 4B coalesced
    xo[t + 256] = pack4(b.x, b.y, b.z, b.w, inv);
}

// ---------- kernel 2: w fp32 -> sign i8 (+1/-1); also zero stat accums ----------
__global__ __launch_bounds__(256) void convert_w_kernel(
        const float4* __restrict__ w, int* __restrict__ wq,
        float4* __restrict__ stats /* colsum[2048]+colsumsq[2048] */) {
    int id = blockIdx.x * 256 + threadIdx.x;       // exact: 4096 blocks
    if (id < 1024) stats[id] = make_float4(0.f, 0.f, 0.f, 0.f);
    float4 a = w[id];
    int b0 = (a.x < 0.f) ? 0xFF : 0x01;
    int b1 = (a.y < 0.f) ? 0xFF : 0x01;
    int b2 = (a.z < 0.f) ? 0xFF : 0x01;
    int b3 = (a.w < 0.f) ? 0xFF : 0x01;
    wq[id] = b0 | (b1 << 8) | (b2 << 16) | (b3 << 24);
}

// ---------- kernel 3: i8 GEMM (NT) 256x256 tile, BK=128, loose 2-barrier loop ----------
// UNCHANGED from round 3 (baseline for the diagnostic dispatches below).
__global__ __launch_bounds__(512, 2) void gemm_bn_kernel(
        const char* __restrict__ A, const char* __restrict__ Bw,
        const float* __restrict__ scales,
        unsigned short* __restrict__ Yb,
        float* __restrict__ colsum, float* __restrict__ colsumsq) {
    __shared__ __align__(16) char smem[131072];  // [2 buf][A 32K | B 32K]

    const int tid  = threadIdx.x;
    const int wave = tid >> 6;
    const int lane = tid & 63;
    const int wm = wave >> 2;         // 0..1 -> 128-row band of M
    const int wn = wave & 3;          // 0..3 -> 64-col band of N
    const int lr = lane & 15;
    const int lq = lane >> 4;

    // XCD swizzle (512 blocks, 512%8==0 -> simple bijection)
    const int b  = blockIdx.x;                 // 0..511
    const int lb = (b & 7) * 64 + (b >> 3);
    const int bm = (lb >> 3) * 256;            // 64 M tiles
    const int bn = (lb & 7) * 256;             // 8 N tiles

    // staging: sweep = 64 rows x 128B; thread row = tid>>3, chunk = tid&7;
    // source chunk = chunk ^ (row&7) (sweep bases %8==0).
    const int swz16 = (((tid & 7) ^ ((tid >> 3) & 7)) << 4);
    const char* gA = A  + (size_t)(bm + (tid >> 3)) * IN_DIM + swz16;
    const char* gB = Bw + (size_t)(bn + (tid >> 3)) * IN_DIM + swz16;
    const int ldst = tid << 4;

    // ds-read: frag (i,kk): row = band + i*16 + lr (x128B), slot = (kk*4+lq)^(lr&7)
    const int aRd = wm * 16384 + lr * 128;
    const int bRd = 32768 + wn * 8192 + lr * 128;
    const int sl0 = ((lq    ) ^ (lr & 7)) << 4;
    const int sl1 = ((lq + 4) ^ (lr & 7)) << 4;

    i32x4 acc[8][4];
#pragma unroll
    for (int i = 0; i < 8; ++i)
#pragma unroll
        for (int j = 0; j < 4; ++j) {
            i32x4 z = {0, 0, 0, 0};
            acc[i][j] = z;
        }

#define VM_WAIT(N) asm volatile("s_waitcnt vmcnt(" #N ")" ::: "memory")
#define BAR()      __builtin_amdgcn_s_barrier()
#define STAGE(buf_, k_) do {                                        \
    char* d = smem + (buf_) * 65536;                                \
    gl_lds16(gA + (k_)          , d + 0 * 8192 + ldst);             \
    gl_lds16(gA + (k_) + 131072 , d + 1 * 8192 + ldst);             \
    gl_lds16(gA + (k_) + 262144 , d + 2 * 8192 + ldst);             \
    gl_lds16(gA + (k_) + 393216 , d + 3 * 8192 + ldst);             \
    gl_lds16(gB + (k_)          , d + 32768 + 0 * 8192 + ldst);     \
    gl_lds16(gB + (k_) + 131072 , d + 32768 + 1 * 8192 + ldst);     \
    gl_lds16(gB + (k_) + 262144 , d + 32768 + 2 * 8192 + ldst);     \
    gl_lds16(gB + (k_) + 393216 , d + 32768 + 3 * 8192 + ldst);     \
} while (0)

    STAGE(0, 0);
    STAGE(1, 128);
    VM_WAIT(8);
    BAR();

    const int NT = IN_DIM / 128;    // 16 K-tiles
#pragma unroll 2
    for (int t = 0; t < NT; ++t) {
        const char* Sb = smem + (t & 1) * 65536;
        {
            i32x4 av[8], bv[4];
#pragma unroll
            for (int i = 0; i < 8; ++i)
                av[i] = *(const i32x4*)(Sb + aRd + i * 2048 + sl0);
#pragma unroll
            for (int j = 0; j < 4; ++j)
                bv[j] = *(const i32x4*)(Sb + bRd + j * 2048 + sl0);
            __builtin_amdgcn_s_setprio(1);
#pragma unroll
            for (int i = 0; i < 8; ++i)
#pragma unroll
                for (int j = 0; j < 4; ++j)
                    acc[i][j] = __builtin_amdgcn_mfma_i32_16x16x64_i8(
                        av[i], bv[j], acc[i][j], 0, 0, 0);
            __builtin_amdgcn_s_setprio(0);
        }
        {
            i32x4 av[8], bv[4];
#pragma unroll
            for (int i = 0; i < 8; ++i)
                av[i] = *(const i32x4*)(Sb + aRd + i * 2048 + sl1);
#pragma unroll
            for (int j = 0; j < 4; ++j)
                bv[j] = *(const i32x4*)(Sb + bRd + j * 2048 + sl1);
            __builtin_amdgcn_s_setprio(1);
#pragma unroll
            for (int i = 0; i < 8; ++i)
#pragma unroll
                for (int j = 0; j < 4; ++j)
                    acc[i][j] = __builtin_amdgcn_mfma_i32_16x16x64_i8(
                        av[i], bv[j], acc[i][j], 0, 0, 0);
            __builtin_amdgcn_s_setprio(0);
        }

        if (t + 2 < NT) {
            BAR();
            STAGE(t & 1, (size_t)(t + 2) * 128);
            VM_WAIT(8);
            BAR();
        } else if (t + 1 < NT) {
            VM_WAIT(0);
            BAR();
        }
    }

#undef STAGE
#undef VM_WAIT
#undef BAR

    // epilogue: y = scales[m] * acc (C/D layout: col = lr, row = lq*4 + r)
    float colS[4], colQ[4];
#pragma unroll
    for (int j = 0; j < 4; ++j) { colS[j] = 0.f; colQ[j] = 0.f; }

#pragma unroll
    for (int i = 0; i < 8; ++i) {
        const int row0 = bm + wm * 128 + i * 16 + lq * 4;
        float sc[4];
#pragma unroll
        for (int r = 0; r < 4; ++r) sc[r] = scales[row0 + r];
#pragma unroll
        for (int r = 0; r < 4; ++r) {
            size_t base = (size_t)(row0 + r) * OUT_DIM + bn + wn * 64 + lr;
#pragma unroll
            for (int j = 0; j < 4; ++j) {
                float v = (float)acc[i][j][r] * sc[r];
                Yb[base + j * 16] = f2bf_rne(v);
                colS[j] += v;
                colQ[j] += v * v;
            }
        }
    }

#pragma unroll
    for (int j = 0; j < 4; ++j) {
        float s = colS[j], q = colQ[j];
        s += __shfl_xor(s, 16); s += __shfl_xor(s, 32);
        q += __shfl_xor(q, 16); q += __shfl_xor(q, 32);
        if (lq == 0) {
            int col = bn + wn * 64 + j * 16 + lr;
            atomicAdd(&colsum[col], s);
            atomicAdd(&colsumsq[col], q);
        }
    }
}

// ---------- DIAGNOSTIC kernels: component ablation of the GEMM window ----------
// MODE 1: ds_read + MFMA + barriers (no staging in loop)
// MODE 2: STAGE + vmcnt + MFMA + barriers (no ds_read in loop; reg operands)
// MODE 3: MFMA + barriers only
// 48 windows each, grid 256 (1 block/CU, 1 round). Output: folded acc to
// scratch (keep-alive). Numerical result is irrelevant; only duration matters.
template<int MODE>
__global__ __launch_bounds__(512, 2) void gemm_diag_kernel(
        const char* __restrict__ A, const char* __restrict__ Bw,
        i32x4* __restrict__ scratch) {
    __shared__ __align__(16) char smem[131072];

    const int tid  = threadIdx.x;
    const int wave = tid >> 6;
    const int lane = tid & 63;
    const int wm = wave >> 2;
    const int wn = wave & 3;
    const int lr = lane & 15;
    const int lq = lane >> 4;

    const int b  = blockIdx.x;                 // 0..255 (no swizzle needed)
    const int bm = (b >> 3) * 256;             // 32 M tiles used
    const int bn = (b & 7) * 256;

    const int swz16 = (((tid & 7) ^ ((tid >> 3) & 7)) << 4);
    const char* gA = A  + (size_t)(bm + (tid >> 3)) * IN_DIM + swz16;
    const char* gB = Bw + (size_t)(bn + (tid >> 3)) * IN_DIM + swz16;
    const int ldst = tid << 4;

    const int aRd = wm * 16384 + lr * 128;
    const int bRd = 32768 + wn * 8192 + lr * 128;
    const int sl0 = ((lq    ) ^ (lr & 7)) << 4;
    const int sl1 = ((lq + 4) ^ (lr & 7)) << 4;

    i32x4 acc[8][4];
#pragma unroll
    for (int i = 0; i < 8; ++i)
#pragma unroll
        for (int j = 0; j < 4; ++j) {
            i32x4 z = {0, 0, 0, 0};
            acc[i][j] = z;
        }

#define VM_WAIT(N) asm volatile("s_waitcnt vmcnt(" #N ")" ::: "memory")
#define BAR()      __builtin_amdgcn_s_barrier()
#define STAGE(buf_, k_) do {                                        \
    char* d = smem + (buf_) * 65536;                                \
    gl_lds16(gA + (k_)          , d + 0 * 8192 + ldst);             \
    gl_lds16(gA + (k_) + 131072 , d + 1 * 8192 + ldst);             \
    gl_lds16(gA + (k_) + 262144 , d + 2 * 8192 + ldst);             \
    gl_lds16(gA + (k_) + 393216 , d + 3 * 8192 + ldst);             \
    gl_lds16(gB + (k_)          , d + 32768 + 0 * 8192 + ldst);     \
    gl_lds16(gB + (k_) + 131072 , d + 32768 + 1 * 8192 + ldst);     \
    gl_lds16(gB + (k_) + 262144 , d + 32768 + 2 * 8192 + ldst);     \
    gl_lds16(gB + (k_) + 393216 , d + 32768 + 3 * 8192 + ldst);     \
} while (0)

    STAGE(0, 0);
    STAGE(1, 128);
    VM_WAIT(0);
    BAR();

    // register-resident operands for MODE 2/3
    i32x4 av0[8], bv0[4];
#pragma unroll
    for (int i = 0; i < 8; ++i)
        av0[i] = *(const i32x4*)(smem + aRd + i * 2048 + sl0);
#pragma unroll
    for (int j = 0; j < 4; ++j)
        bv0[j] = *(const i32x4*)(smem + bRd + j * 2048 + sl0);

    const int WINDOWS = 48;
    for (int w = 0; w < WINDOWS; ++w) {
        if (MODE == 1) {
            // ds_read + MFMA window (same as full, no staging)
            const char* Sb = smem + (w & 1) * 65536;
            {
                i32x4 av[8], bv[4];
#pragma unroll
                for (int i = 0; i < 8; ++i)
                    av[i] = *(const i32x4*)(Sb + aRd + i * 2048 + sl0);
#pragma unroll
                for (int j = 0; j < 4; ++j)
                    bv[j] = *(const i32x4*)(Sb + bRd + j * 2048 + sl0);
                __builtin_amdgcn_s_setprio(1);
#pragma unroll
                for (int i = 0; i < 8; ++i)
#pragma unroll
                    for (int j = 0; j < 4; ++j)
                        acc[i][j] = __builtin_amdgcn_mfma_i32_16x16x64_i8(
                            av[i], bv[j], acc[i][j], 0, 0, 0);
                __builtin_amdgcn_s_setprio(0);
            }
            {
                i32x4 av[8], bv[4];
#pragma unroll
                for (int i = 0; i < 8; ++i)
                    av[i] = *(const i32x4*)(Sb + aRd + i * 2048 + sl1);
#pragma unroll
                for (int j = 0; j < 4; ++j)
                    bv[j] = *(const i32x4*)(Sb + bRd + j * 2048 + sl1);
                __builtin_amdgcn_s_setprio(1);
#pragma unroll
                for (int i = 0; i < 8; ++i)
#pragma unroll
                    for (int j = 0; j < 4; ++j)
                        acc[i][j] = __builtin_amdgcn_mfma_i32_16x16x64_i8(
                            av[i], bv[j], acc[i][j], 0, 0, 0);
                __builtin_amdgcn_s_setprio(0);
            }
            BAR();
            BAR();
        } else {
            // MODE 2/3: MFMA on register operands (2 x 32 = 64 MFMA/window)
            __builtin_amdgcn_s_setprio(1);
#pragma unroll
            for (int r = 0; r < 2; ++r)
#pragma unroll
                for (int i = 0; i < 8; ++i)
#pragma unroll
                    for (int j = 0; j < 4; ++j)
                        acc[i][j] = __builtin_amdgcn_mfma_i32_16x16x64_i8(
                            av0[i], bv0[j], acc[i][j], 0, 0, 0);
            __builtin_amdgcn_s_setprio(0);
            if (MODE == 2) {
                BAR();
                STAGE(w & 1, (w & 1) ? 128 : 0);
                VM_WAIT(8);
                BAR();
            } else {
                BAR();
                BAR();
            }
        }
    }

#undef STAGE
#undef VM_WAIT
#undef BAR

    // keep-alive: fold acc and store once
    i32x4 r = {0, 0, 0, 0};
#pragma unroll
    for (int i = 0; i < 8; ++i)
#pragma unroll
        for (int j = 0; j < 4; ++j)
            r += acc[i][j];
    scratch[(size_t)b * 512 + tid] = r;
}

// ---------- kernel 4: finalize BN params ----------
__global__ __launch_bounds__(256) void finalize_kernel(
        const float* __restrict__ colsum, const float* __restrict__ colsumsq,
        const float* __restrict__ gamma, const float* __restrict__ beta,
        float* __restrict__ scale, float* __restrict__ bias) {
    int n = blockIdx.x * 256 + threadIdx.x;
    if (n < OUT_DIM) {
        const float inv = 1.f / (float)B_DIM;
        float mean = colsum[n] * inv;
        float var  = colsumsq[n] * inv - mean * mean;
        float sc   = gamma[n] * rsqrtf(var + BN_EPS);
        scale[n] = sc;
        bias[n]  = beta[n] - mean * sc;
    }
}

// ---------- kernel 5: bf16 Y -> affine+ReLU -> fp32 out. 8 elems/thread ----------
__global__ __launch_bounds__(256) void bn_relu_bf16_kernel(
        const u16x4* __restrict__ yb, float4* __restrict__ out,
        const float4* __restrict__ scale4, const float4* __restrict__ bias4) {
    int base = blockIdx.x * 512 + threadIdx.x;   // block covers 512 f4-groups
#pragma unroll
    for (int p = 0; p < 2; ++p) {
        int id = base + p * 256;                 // coalesced both passes
        int c4 = id & (OUT_DIM / 4 - 1);         // column group (2048%4==0)
        u16x4 h = yb[id];                        // 8B coalesced read
        float4 s = scale4[c4];
        float4 bb = bias4[c4];
        float4 v;
        v.x = fmaxf(fmaf(bf2f(h[0]), s.x, bb.x), 0.f);
        v.y = fmaxf(fmaf(bf2f(h[1]), s.y, bb.y), 0.f);
        v.z = fmaxf(fmaf(bf2f(h[2]), s.z, bb.z), 0.f);
        v.w = fmaxf(fmaf(bf2f(h[3]), s.w, bb.w), 0.f);
        out[id] = v;                             // 16B coalesced write
    }
}

// ---------- launch ----------
extern "C" void kernel_launch(void* const* d_in, const int* in_sizes, int n_in,
                              void* d_out, int out_size, void* d_ws, size_t ws_size,
                              hipStream_t stream) {
    const float* x     = (const float*)d_in[0];   // [16384, 2048]
    const float* w     = (const float*)d_in[1];   // [2048, 2048]
    const float* gamma = (const float*)d_in[2];   // [2048]
    const float* beta  = (const float*)d_in[3];   // [2048]
    float* out = (float*)d_out;                   // [16384, 2048]

    char* ws = (char*)d_ws;
    // ws layout: xq 32MB | wq 4MB | yb 64MB | stats 32KB | scales 64KB
    const size_t XQ_OFF = 0;
    const size_t WQ_OFF = XQ_OFF + (size_t)B_DIM * IN_DIM;          // 33,554,432
    const size_t YB_OFF = WQ_OFF + (size_t)OUT_DIM * IN_DIM;        // 37,748,736
    const size_t ST_OFF = YB_OFF + (size_t)B_DIM * OUT_DIM * 2;     // 104,857,600
    const size_t SC_OFF = ST_OFF + 8192 * 4;                        // 104,890,368

    char* xq = ws + XQ_OFF;
    char* wq = ws + WQ_OFF;
    unsigned short* yb = (unsigned short*)(ws + YB_OFF);
    float* colsum   = (float*)(ws + ST_OFF);
    float* colsumsq = colsum + 2048;
    float* scale    = colsum + 4096;
    float* bias     = colsum + 6144;
    float* scales   = (float*)(ws + SC_OFF);      // per-row x scales [16384]

    quantize_x_kernel<<<B_DIM, 256, 0, stream>>>(
        (const float4*)x, (int*)xq, scales);
    convert_w_kernel<<<4096, 256, 0, stream>>>(
        (const float4*)w, (int*)wq, (float4*)colsum);
    gemm_bn_kernel<<<512, 512, 0, stream>>>(
        xq, wq, scales, yb, colsum, colsumsq);
    finalize_kernel<<<8, 256, 0, stream>>>(
        colsum, colsumsq, gamma, beta, scale, bias);
    bn_relu_bf16_kernel<<<16384, 256, 0, stream>>>(
        (const u16x4*)yb, (float4*)out, (const float4*)scale,
        (const float4*)bias);

    // ---- diagnostic dispatches (timing only; scratch = yb region, which the
    // real gemm fully rewrites each replay, so correctness is unaffected) ----
    i32x4* diag_scratch = (i32x4*)(ws + YB_OFF);
    gemm_diag_kernel<1><<<256, 512, 0, stream>>>(xq, wq, diag_scratch);
    gemm_diag_kernel<2><<<256, 512, 0, stream>>>(xq, wq, diag_scratch);
    gemm_diag_kernel<3><<<256, 512, 0, stream>>>(xq, wq, diag_scratch);
}

// Round 6
// 375.532 us; speedup vs baseline: 1.3667x; 1.3667x over previous
//
#include <hip/hip_runtime.h>
#include <stdint.h>

// Problem constants (from reference setup_inputs)
#define B_DIM   16384
#define IN_DIM  2048
#define OUT_DIM 2048
#define BN_EPS  1e-5f

typedef int    i32x4 __attribute__((ext_vector_type(4)));
typedef unsigned short u16x4 __attribute__((ext_vector_type(4)));

// ---------- helpers ----------

__device__ __forceinline__ unsigned short f2bf_rne(float f) {
    unsigned u = __builtin_bit_cast(unsigned, f);
    return (unsigned short)((u + 0x7fffu + ((u >> 16) & 1u)) >> 16);
}
__device__ __forceinline__ float bf2f(unsigned short h) {
    unsigned u = ((unsigned)h) << 16;
    return __builtin_bit_cast(float, u);
}

// async global->LDS, 16B per lane. LDS dst = wave-uniform base + lane*16.
__device__ __forceinline__ void gl_lds16(const void* g, void* l) {
    __builtin_amdgcn_global_load_lds(
        (const __attribute__((address_space(1))) unsigned int*)g,
        (__attribute__((address_space(3))) unsigned int*)l,
        16, 0, 0);
}

__device__ __forceinline__ int pack4(float a, float b, float c, float d, float inv) {
    int q0 = (int)rintf(a * inv) & 255;
    int q1 = (int)rintf(b * inv) & 255;
    int q2 = (int)rintf(c * inv) & 255;
    int q3 = (int)rintf(d * inv) & 255;
    return q0 | (q1 << 8) | (q2 << 16) | (q3 << 24);
}

// ---------- kernel 1: x fp32 -> i8 with per-row scale ----------
__global__ __launch_bounds__(256) void quantize_x_kernel(
        const float4* __restrict__ x4, int* __restrict__ xq,
        float* __restrict__ scales) {
    __shared__ float wmax[4];
    const int row = blockIdx.x;
    const int t = threadIdx.x;
    const float4* xr = x4 + (size_t)row * 512;
    float4 a = xr[t];          // 16B coalesced
    float4 b = xr[t + 256];
    float m = fmaxf(fmaxf(fabsf(a.x), fabsf(a.y)), fmaxf(fabsf(a.z), fabsf(a.w)));
    m = fmaxf(m, fmaxf(fmaxf(fabsf(b.x), fabsf(b.y)), fmaxf(fabsf(b.z), fabsf(b.w))));
#pragma unroll
    for (int off = 32; off >= 1; off >>= 1) m = fmaxf(m, __shfl_xor(m, off));
    if ((t & 63) == 0) wmax[t >> 6] = m;
    __syncthreads();
    m = fmaxf(fmaxf(wmax[0], wmax[1]), fmaxf(wmax[2], wmax[3]));
    m = fmaxf(m, 1e-20f);                 // guard all-zero row
    const float inv = 127.0f / m;
    if (t == 0) scales[row] = m * (1.0f / 127.0f);
    int* xo = xq + (size_t)row * 512;
    xo[t]       = pack4(a.x, a.y, a.z, a.w, inv);   // 4B coalesced
    xo[t + 256] = pack4(b.x, b.y, b.z, b.w, inv);
}

// ---------- kernel 2: w fp32 -> sign i8 (+1/-1); also zero stat accums ----------
__global__ __launch_bounds__(256) void convert_w_kernel(
        const float4* __restrict__ w, int* __restrict__ wq,
        float4* __restrict__ stats /* colsum[2048]+colsumsq[2048] */) {
    int id = blockIdx.x * 256 + threadIdx.x;       // exact: 4096 blocks
    if (id < 1024) stats[id] = make_float4(0.f, 0.f, 0.f, 0.f);
    float4 a = w[id];
    int b0 = (a.x < 0.f) ? 0xFF : 0x01;
    int b1 = (a.y < 0.f) ? 0xFF : 0x01;
    int b2 = (a.z < 0.f) ? 0xFF : 0x01;
    int b3 = (a.w < 0.f) ? 0xFF : 0x01;
    wq[id] = b0 | (b1 << 8) | (b2 << 16) | (b3 << 24);
}

// ---------- shared geometry for the GEMM & its staging diagnostic ----------
// Tile 256(M) x 128(N), BK=128 bytes, 16 K-tiles. Grid 1024 = 64 bm x 16 bn.
// Round-4 ablation: MFMA/ds_read/stage each healthy in isolation; the binder
// is staging SERVICE BANDWIDTH: per-XCD concurrent working set was 6MB > 4MB
// L2 -> staging falls to L3 (~300MB/dispatch at ~6.5 TB/s ~= the 80us wall).
// Fix: group swizzle so each XCD's 32 concurrent blocks cover 4 bm x 8 bn:
//   A 4x512KB + B 8x256KB = 4.0 MB = exactly L2. Consecutive rounds keep the
//   same A-quad (bn-half alternates) so A stays L2-hot across 2 rounds.
// Map: x=b&7 (XCD), j=(b>>3)&31 (slot), r=b>>8 (round); g=x*4+r;
//   bm=((g>>1)*4 + (j>>3))*256 ; bn=((g&1)*8 + (j&7))*128   (bijective)
__device__ __forceinline__ void tile_coords(int b, int& bm, int& bn) {
    const int x = b & 7;
    const int j = (b >> 3) & 31;
    const int r = b >> 8;
    const int g = x * 4 + r;
    bm = ((g >> 1) * 4 + (j >> 3)) * 256;
    bn = ((g & 1) * 8 + (j & 7)) * 128;
}

// ---------- kernel 3: i8 GEMM (NT) 256x128 tile, L2-resident staging ----------
__global__ __launch_bounds__(512, 1) void gemm_bn_kernel(
        const char* __restrict__ A, const char* __restrict__ Bw,
        const float* __restrict__ scales,
        unsigned short* __restrict__ Yb,
        float* __restrict__ colsum, float* __restrict__ colsumsq) {
    // per buffer: A[256][128B] = 32KB at +0, B[128][128B] = 16KB at +32768
    __shared__ __align__(16) char smem[2 * 49152];   // 96 KiB -> 1 block/CU

    const int tid  = threadIdx.x;
    const int wave = tid >> 6;
    const int lane = tid & 63;
    const int wm = wave >> 1;         // 0..3 -> 64-row band of M
    const int wn = wave & 1;          // 0..1 -> 64-col band of N
    const int lr = lane & 15;
    const int lq = lane >> 4;

    int bm, bn;
    tile_coords(blockIdx.x, bm, bn);

    // staging: sweep = 64 rows x 128B = 8KB = 512 thr x 16B; thread row =
    // tid>>3, chunk = tid&7; source chunk = chunk ^ (row&7).
    const int swz16 = (((tid & 7) ^ ((tid >> 3) & 7)) << 4);
    const char* gA = A  + (size_t)(bm + (tid >> 3)) * IN_DIM + swz16;
    const char* gB = Bw + (size_t)(bn + (tid >> 3)) * IN_DIM + swz16;
    const int ldst = tid << 4;

    // ds-read: frag (i,kk): row = band + i*16 + lr (x128B), slot = (kk*4+lq)^(lr&7)
    const int aRd = wm * 8192 + lr * 128;             // A at +0
    const int bRd = 32768 + wn * 8192 + lr * 128;     // B at +32768
    const int sl0 = ((lq    ) ^ (lr & 7)) << 4;
    const int sl1 = ((lq + 4) ^ (lr & 7)) << 4;

    i32x4 acc[4][4];
#pragma unroll
    for (int i = 0; i < 4; ++i)
#pragma unroll
        for (int j = 0; j < 4; ++j) {
            i32x4 z = {0, 0, 0, 0};
            acc[i][j] = z;
        }

#define VM_WAIT(N) asm volatile("s_waitcnt vmcnt(" #N ")" ::: "memory")
#define BAR()      __builtin_amdgcn_s_barrier()
// stage one 48KB K-tile (A 32K + B 16K): 6 sweeps
#define STAGE(buf_, k_) do {                                        \
    char* d = smem + (buf_) * 49152;                                \
    gl_lds16(gA + (k_)          , d + 0 * 8192 + ldst);             \
    gl_lds16(gA + (k_) + 131072 , d + 1 * 8192 + ldst);             \
    gl_lds16(gA + (k_) + 262144 , d + 2 * 8192 + ldst);             \
    gl_lds16(gA + (k_) + 393216 , d + 3 * 8192 + ldst);             \
    gl_lds16(gB + (k_)          , d + 32768 + 0 * 8192 + ldst);     \
    gl_lds16(gB + (k_) + 131072 , d + 32768 + 1 * 8192 + ldst);     \
} while (0)

    // prologue: tiles 0,1 -> buffers 0,1; drain tile 0's 6 loads only
    STAGE(0, 0);
    STAGE(1, 128);
    VM_WAIT(6);
    BAR();

    const int NT = IN_DIM / 128;    // 16 K-tiles
    for (int t = 0; t < NT; ++t) {
        const char* Sb = smem + (t & 1) * 49152;
        // ---- kk = 0 ----
        {
            i32x4 av[4], bv[4];
#pragma unroll
            for (int i = 0; i < 4; ++i)
                av[i] = *(const i32x4*)(Sb + aRd + i * 2048 + sl0);
#pragma unroll
            for (int j = 0; j < 4; ++j)
                bv[j] = *(const i32x4*)(Sb + bRd + j * 2048 + sl0);
            __builtin_amdgcn_s_setprio(1);
#pragma unroll
            for (int i = 0; i < 4; ++i)
#pragma unroll
                for (int j = 0; j < 4; ++j)
                    acc[i][j] = __builtin_amdgcn_mfma_i32_16x16x64_i8(
                        av[i], bv[j], acc[i][j], 0, 0, 0);
            __builtin_amdgcn_s_setprio(0);
        }
        // ---- kk = 1 ----
        {
            i32x4 av[4], bv[4];
#pragma unroll
            for (int i = 0; i < 4; ++i)
                av[i] = *(const i32x4*)(Sb + aRd + i * 2048 + sl1);
#pragma unroll
            for (int j = 0; j < 4; ++j)
                bv[j] = *(const i32x4*)(Sb + bRd + j * 2048 + sl1);
            __builtin_amdgcn_s_setprio(1);
#pragma unroll
            for (int i = 0; i < 4; ++i)
#pragma unroll
                for (int j = 0; j < 4; ++j)
                    acc[i][j] = __builtin_amdgcn_mfma_i32_16x16x64_i8(
                        av[i], bv[j], acc[i][j], 0, 0, 0);
            __builtin_amdgcn_s_setprio(0);
        }

        if (t + 2 < NT) {
            BAR();                               // all waves done reading Sb
            STAGE(t & 1, (size_t)(t + 2) * 128); // overwrite with tile t+2
            VM_WAIT(6);                          // drain t+1; t+2 in flight
            BAR();                               // t+1 visible to all waves
        } else if (t + 1 < NT) {
            VM_WAIT(0);                          // drain final tile's loads
            BAR();
        }
    }

#undef STAGE
#undef VM_WAIT
#undef BAR

    // epilogue: y = scales[m] * acc (C/D layout: col = lr, row = lq*4 + r)
    float colS[4], colQ[4];
#pragma unroll
    for (int j = 0; j < 4; ++j) { colS[j] = 0.f; colQ[j] = 0.f; }

#pragma unroll
    for (int i = 0; i < 4; ++i) {
        const int row0 = bm + wm * 64 + i * 16 + lq * 4;
        float sc[4];
#pragma unroll
        for (int r = 0; r < 4; ++r) sc[r] = scales[row0 + r];
#pragma unroll
        for (int r = 0; r < 4; ++r) {
            size_t base = (size_t)(row0 + r) * OUT_DIM + bn + wn * 64 + lr;
#pragma unroll
            for (int j = 0; j < 4; ++j) {
                float v = (float)acc[i][j][r] * sc[r];
                Yb[base + j * 16] = f2bf_rne(v);
                colS[j] += v;
                colQ[j] += v * v;
            }
        }
    }

    // per-column partial sum / sumsq -> atomics (combine 4 quads = 4 row groups)
#pragma unroll
    for (int j = 0; j < 4; ++j) {
        float s = colS[j], q = colQ[j];
        s += __shfl_xor(s, 16); s += __shfl_xor(s, 32);
        q += __shfl_xor(q, 16); q += __shfl_xor(q, 32);
        if (lq == 0) {
            int col = bn + wn * 64 + j * 16 + lr;
            atomicAdd(&colsum[col], s);
            atomicAdd(&colsumsq[col], q);
        }
    }
}

// ---------- DIAGNOSTIC: exact staging replica of gemm_bn (no MFMA/ds_read) ----
// Same grid/swizzle/addresses/vmcnt discipline. Duration ~= the staging
// service time alone. If ~15-25us: locality works, staging hidden. If ~70us:
// staging BW binds regardless -> next lever is traffic reduction.
__global__ __launch_bounds__(512, 1) void stage_diag_kernel(
        const char* __restrict__ A, const char* __restrict__ Bw,
        i32x4* __restrict__ scratch) {
    __shared__ __align__(16) char smem[2 * 49152];

    const int tid = threadIdx.x;
    int bm, bn;
    tile_coords(blockIdx.x, bm, bn);

    const int swz16 = (((tid & 7) ^ ((tid >> 3) & 7)) << 4);
    const char* gA = A  + (size_t)(bm + (tid >> 3)) * IN_DIM + swz16;
    const char* gB = Bw + (size_t)(bn + (tid >> 3)) * IN_DIM + swz16;
    const int ldst = tid << 4;

#define VM_WAIT(N) asm volatile("s_waitcnt vmcnt(" #N ")" ::: "memory")
#define BAR()      __builtin_amdgcn_s_barrier()
#define STAGE(buf_, k_) do {                                        \
    char* d = smem + (buf_) * 49152;                                \
    gl_lds16(gA + (k_)          , d + 0 * 8192 + ldst);             \
    gl_lds16(gA + (k_) + 131072 , d + 1 * 8192 + ldst);             \
    gl_lds16(gA + (k_) + 262144 , d + 2 * 8192 + ldst);             \
    gl_lds16(gA + (k_) + 393216 , d + 3 * 8192 + ldst);             \
    gl_lds16(gB + (k_)          , d + 32768 + 0 * 8192 + ldst);     \
    gl_lds16(gB + (k_) + 131072 , d + 32768 + 1 * 8192 + ldst);     \
} while (0)

    STAGE(0, 0);
    STAGE(1, 128);
    VM_WAIT(6);
    BAR();

    const int NT = IN_DIM / 128;
    for (int t = 0; t < NT; ++t) {
        if (t + 2 < NT) {
            BAR();
            STAGE(t & 1, (size_t)(t + 2) * 128);
            VM_WAIT(6);
            BAR();
        } else if (t + 1 < NT) {
            VM_WAIT(0);
            BAR();
        }
    }
#undef STAGE
#undef VM_WAIT
#undef BAR

    // keep-alive: read back one 16B chunk per thread, store once
    i32x4 v = *(const i32x4*)(smem + (tid << 4));
    i32x4 w = *(const i32x4*)(smem + 49152 + (tid << 4));
    scratch[(size_t)blockIdx.x * 512 + tid] = v + w;
}

// ---------- kernel 4: finalize BN params ----------
__global__ __launch_bounds__(256) void finalize_kernel(
        const float* __restrict__ colsum, const float* __restrict__ colsumsq,
        const float* __restrict__ gamma, const float* __restrict__ beta,
        float* __restrict__ scale, float* __restrict__ bias) {
    int n = blockIdx.x * 256 + threadIdx.x;
    if (n < OUT_DIM) {
        const float inv = 1.f / (float)B_DIM;
        float mean = colsum[n] * inv;
        float var  = colsumsq[n] * inv - mean * mean;
        float sc   = gamma[n] * rsqrtf(var + BN_EPS);
        scale[n] = sc;
        bias[n]  = beta[n] - mean * sc;
    }
}

// ---------- kernel 5: bf16 Y -> affine+ReLU -> fp32 out. 8 elems/thread ----------
__global__ __launch_bounds__(256) void bn_relu_bf16_kernel(
        const u16x4* __restrict__ yb, float4* __restrict__ out,
        const float4* __restrict__ scale4, const float4* __restrict__ bias4) {
    int base = blockIdx.x * 512 + threadIdx.x;   // block covers 512 f4-groups
#pragma unroll
    for (int p = 0; p < 2; ++p) {
        int id = base + p * 256;                 // coalesced both passes
        int c4 = id & (OUT_DIM / 4 - 1);         // column group (2048%4==0)
        u16x4 h = yb[id];                        // 8B coalesced read
        float4 s = scale4[c4];
        float4 bb = bias4[c4];
        float4 v;
        v.x = fmaxf(fmaf(bf2f(h[0]), s.x, bb.x), 0.f);
        v.y = fmaxf(fmaf(bf2f(h[1]), s.y, bb.y), 0.f);
        v.z = fmaxf(fmaf(bf2f(h[2]), s.z, bb.z), 0.f);
        v.w = fmaxf(fmaf(bf2f(h[3]), s.w, bb.w), 0.f);
        out[id] = v;                             // 16B coalesced write
    }
}

// ---------- launch ----------
extern "C" void kernel_launch(void* const* d_in, const int* in_sizes, int n_in,
                              void* d_out, int out_size, void* d_ws, size_t ws_size,
                              hipStream_t stream) {
    const float* x     = (const float*)d_in[0];   // [16384, 2048]
    const float* w     = (const float*)d_in[1];   // [2048, 2048]
    const float* gamma = (const float*)d_in[2];   // [2048]
    const float* beta  = (const float*)d_in[3];   // [2048]
    float* out = (float*)d_out;                   // [16384, 2048]

    char* ws = (char*)d_ws;
    // ws layout: xq 32MB | wq 4MB | yb 64MB | stats 32KB | scales 64KB
    const size_t XQ_OFF = 0;
    const size_t WQ_OFF = XQ_OFF + (size_t)B_DIM * IN_DIM;          // 33,554,432
    const size_t YB_OFF = WQ_OFF + (size_t)OUT_DIM * IN_DIM;        // 37,748,736
    const size_t ST_OFF = YB_OFF + (size_t)B_DIM * OUT_DIM * 2;     // 104,857,600
    const size_t SC_OFF = ST_OFF + 8192 * 4;                        // 104,890,368

    char* xq = ws + XQ_OFF;
    char* wq = ws + WQ_OFF;
    unsigned short* yb = (unsigned short*)(ws + YB_OFF);
    float* colsum   = (float*)(ws + ST_OFF);
    float* colsumsq = colsum + 2048;
    float* scale    = colsum + 4096;
    float* bias     = colsum + 6144;
    float* scales   = (float*)(ws + SC_OFF);      // per-row x scales [16384]

    quantize_x_kernel<<<B_DIM, 256, 0, stream>>>(
        (const float4*)x, (int*)xq, scales);
    convert_w_kernel<<<4096, 256, 0, stream>>>(
        (const float4*)w, (int*)wq, (float4*)colsum);
    gemm_bn_kernel<<<1024, 512, 0, stream>>>(
        xq, wq, scales, yb, colsum, colsumsq);
    finalize_kernel<<<8, 256, 0, stream>>>(
        colsum, colsumsq, gamma, beta, scale, bias);
    bn_relu_bf16_kernel<<<16384, 256, 0, stream>>>(
        (const u16x4*)yb, (float4*)out, (const float4*)scale,
        (const float4*)bias);

    // ---- staging diagnostic (timing only; scratch = yb region, fully
    // rewritten by the real gemm each replay, so correctness is unaffected) ----
    stage_diag_kernel<<<1024, 512, 0, stream>>>(
        xq, wq, (i32x4*)(ws + YB_OFF));
}